// Round 4
// baseline (548.508 us; speedup 1.0000x reference)
//
#include <hip/hip_runtime.h>

#define F_IN 128
#define F_OUT 64
#define NCHUNK 256   // scan chunks per relation

typedef float f32x2 __attribute__((ext_vector_type(2)));
typedef float f32x4 __attribute__((ext_vector_type(4)));
typedef short bf16x8 __attribute__((ext_vector_type(8)));

__device__ __forceinline__ unsigned short f2bf(float f) {
    unsigned int u = __float_as_uint(f);
    u += 0x7fff + ((u >> 16) & 1);          // round-nearest-even
    return (unsigned short)(u >> 16);
}
__device__ __forceinline__ float bf2f(unsigned short s) {
    return __uint_as_float((unsigned int)s << 16);
}

// ---------------- degree (dst occurrences; +1 self-loop added later) --------
__global__ __launch_bounds__(256) void deg_kernel(const int* __restrict__ ei,
                                                  int* __restrict__ deg,
                                                  int N, int E) {
    int r = blockIdx.y;
    int e = blockIdx.x * 256 + threadIdx.x;
    if (e >= E) return;
    int d = ei[(size_t)r * 2 * E + E + e];
    atomicAdd(&deg[(size_t)r * N + d], 1);
}

// ---------------- invperm: ip[perm[i]] = i ----------------------------------
__global__ __launch_bounds__(256) void invperm_kernel(const int* __restrict__ perm,
                                                      int* __restrict__ ip, int N) {
    int r = blockIdx.y;
    int i = blockIdx.x * 256 + threadIdx.x;
    if (i >= N) return;
    ip[(size_t)r * N + perm[(size_t)r * N + i]] = i;
}

// ---------------- hierarchical scan, phase 1: per-chunk sums ----------------
__global__ __launch_bounds__(256) void scan_partial(const int* __restrict__ deg,
                                                    int* __restrict__ psum,
                                                    int N, int chunk) {
    int r = blockIdx.y, b = blockIdx.x;
    int start = b * chunk, end = min(start + chunk, N);
    int s = 0;
    for (int i = start + threadIdx.x; i < end; i += 256)
        s += deg[(size_t)r * N + i];
    __shared__ int ls[256];
    ls[threadIdx.x] = s;
    __syncthreads();
    for (int off = 128; off > 0; off >>= 1) {
        if (threadIdx.x < off) ls[threadIdx.x] += ls[threadIdx.x + off];
        __syncthreads();
    }
    if (threadIdx.x == 0) psum[r * NCHUNK + b] = ls[0];
}

// ---------------- phase 2: exclusive scan of chunk sums (1 block) -----------
__global__ __launch_bounds__(256) void scan_offsets(int* __restrict__ psum,
                                                    int* __restrict__ rowstart,
                                                    int N, int R) {
    int tid = threadIdx.x, lane = tid & 63, wv = tid >> 6;
    __shared__ int wsum[4];
    for (int r = 0; r < R; ++r) {
        int v = psum[r * NCHUNK + tid];
        int sc = v;
        #pragma unroll
        for (int off = 1; off < 64; off <<= 1) {
            int t = __shfl_up(sc, off, 64);
            if (lane >= off) sc += t;
        }
        if (lane == 63) wsum[wv] = sc;
        __syncthreads();
        int woff = 0;
        for (int w = 0; w < wv; ++w) woff += wsum[w];
        psum[r * NCHUNK + tid] = woff + sc - v;   // exclusive
        if (tid == 255) rowstart[(size_t)r * (N + 1) + N] = woff + sc;  // total
        __syncthreads();
    }
}

// ---------------- phase 3: re-scan chunk, write rowstart/cursor/dinv --------
__global__ __launch_bounds__(256) void scan_apply(int* __restrict__ deg,
                                                  const int* __restrict__ psum,
                                                  int* __restrict__ rowstart,
                                                  float* __restrict__ dinv,
                                                  int N, int chunk) {
    int r = blockIdx.y, b = blockIdx.x;
    int tid = threadIdx.x, lane = tid & 63, wv = tid >> 6;
    int start = b * chunk, end = min(start + chunk, N);
    int* dg = deg + (size_t)r * N;
    int* rs = rowstart + (size_t)r * (N + 1);
    float* dv = dinv + (size_t)r * N;
    __shared__ int wsum[4];
    int v[4]; int tsum = 0;
    #pragma unroll
    for (int j = 0; j < 4; ++j) {
        int idx = start + tid * 4 + j;
        v[j] = (idx < end) ? dg[idx] : 0;
        tsum += v[j];
    }
    int sc = tsum;
    #pragma unroll
    for (int off = 1; off < 64; off <<= 1) {
        int t = __shfl_up(sc, off, 64);
        if (lane >= off) sc += t;
    }
    if (lane == 63) wsum[wv] = sc;
    __syncthreads();
    int woff = 0;
    for (int w = 0; w < wv; ++w) woff += wsum[w];
    int excl = psum[r * NCHUNK + b] + woff + sc - tsum;
    #pragma unroll
    for (int j = 0; j < 4; ++j) {
        int idx = start + tid * 4 + j;
        if (idx < end) {
            rs[idx] = excl;
            dg[idx] = excl;                       // cursor for fill_csr
            dv[idx] = rsqrtf((float)(v[j] + 1));  // +1 self-loop
        }
        excl += v[j];
    }
}

// ---------------- fill CSR: bucket by dst; store (src, norm) ----------------
__global__ __launch_bounds__(256) void fill_csr(const int* __restrict__ ei,
                                                const float* __restrict__ dinv,
                                                int* __restrict__ cursor,
                                                int2* __restrict__ csr,
                                                int N, int E) {
    int r = blockIdx.y;
    int e = blockIdx.x * 256 + threadIdx.x;
    if (e >= E) return;
    const int* base = ei + (size_t)r * 2 * E;
    int s = base[e], d = base[E + e];
    const float* dv = dinv + (size_t)r * N;
    float nrm = dv[s] * dv[d];
    int pos = atomicAdd(&cursor[(size_t)r * N + d], 1);
    int2 sp; sp.x = s; sp.y = __float_as_int(nrm);
    csr[(size_t)r * E + pos] = sp;
}

// ---------------- W prep: W[r][k][c] f32 -> wt_hi/wt_lo[r][c][k] bf16 -------
// hi = bf16(w), lo = bf16(w - hi): 3-product MFMA split gives ~2^-16 rel acc.
__global__ __launch_bounds__(256) void w_convert(const float* __restrict__ W,
                                                 unsigned short* __restrict__ wt_hi,
                                                 unsigned short* __restrict__ wt_lo,
                                                 int R) {
    int idx = blockIdx.x * 256 + threadIdx.x;      // over R*64*128
    if (idx >= R * 64 * 128) return;
    int k = idx & 127, c = (idx >> 7) & 63, r = idx >> 13;
    float v = W[((size_t)r * F_IN + k) * F_OUT + c];
    unsigned short h = f2bf(v);
    wt_hi[idx] = h;
    wt_lo[idx] = f2bf(v - bf2f(h));
}

// ---------------- MFMA GEMM: combined[i] = bf16(x @ W_r), pos+neg halves ----
// One block = 128 x-rows, loops all R relations (x staged once: 51.2 MB total
// x traffic instead of 153.6). Operands swapped (A = W^T tile, B = x^T tile)
// so D's reg index = 4 consecutive OUTPUT CHANNELS per lane -> ushort4 stores.
// mfma_f32_16x16x32_bf16: A row=lane&15 (=out ch), B col=lane&15 (=x row),
// k = (lane>>4)*8 + j; D: col=lane&15 (=x row), row=(lane>>4)*4+reg (=out ch).
__global__ __launch_bounds__(256) void gemm_xw_mfma(const float* __restrict__ x,
                                                    const unsigned short* __restrict__ wt_hi,
                                                    const unsigned short* __restrict__ wt_lo,
                                                    const int* __restrict__ ip,
                                                    unsigned short* __restrict__ combined,
                                                    int N, int R) {
    constexpr int KP = 136;  // row stride: 272B = 16B-aligned, bank shift 4 (2-way, free)
    __shared__ __align__(16) unsigned short xs_hi[128 * KP];
    __shared__ __align__(16) unsigned short xs_lo[128 * KP];

    int row0 = blockIdx.x * 128;
    int tid = threadIdx.x;
    {   // stage x tile as bf16 hi/lo: thread -> (row = tid>>1, 64-col half)
        int rr = tid >> 1, half = tid & 1;
        int grow = row0 + rr; if (grow >= N) grow = N - 1;   // clamp, never stored
        const float* xr = x + (size_t)grow * F_IN + half * 64;
        unsigned short* dh = &xs_hi[rr * KP + half * 64];
        unsigned short* dl = &xs_lo[rr * KP + half * 64];
        #pragma unroll
        for (int c = 0; c < 64; c += 4) {
            float4 v = *(const float4*)(xr + c);
            unsigned short h0 = f2bf(v.x), h1 = f2bf(v.y),
                           h2 = f2bf(v.z), h3 = f2bf(v.w);
            ushort4 hv; hv.x = h0; hv.y = h1; hv.z = h2; hv.w = h3;
            *(ushort4*)(dh + c) = hv;
            ushort4 lv;
            lv.x = f2bf(v.x - bf2f(h0)); lv.y = f2bf(v.y - bf2f(h1));
            lv.z = f2bf(v.z - bf2f(h2)); lv.w = f2bf(v.w - bf2f(h3));
            *(ushort4*)(dl + c) = lv;
        }
    }
    __syncthreads();

    int wv = tid >> 6, lane = tid & 63;
    int l15 = lane & 15, lhi = lane >> 4;
    int nbase = wv * 32;                        // wave owns 32 x-rows
    for (int r = 0; r < R; ++r) {
        f32x4 acc[2][4];
        #pragma unroll
        for (int nt = 0; nt < 2; ++nt)
            #pragma unroll
            for (int ct = 0; ct < 4; ++ct)
                acc[nt][ct] = (f32x4){0.f, 0.f, 0.f, 0.f};
        const unsigned short* wh = wt_hi + (size_t)r * 64 * 128;
        const unsigned short* wl = wt_lo + (size_t)r * 64 * 128;
        #pragma unroll
        for (int kc = 0; kc < 4; ++kc) {
            int kb = kc * 32 + lhi * 8;
            bf16x8 bh[2], bl[2], ah[4], al[4];
            #pragma unroll
            for (int nt = 0; nt < 2; ++nt) {
                int ro = (nbase + nt * 16 + l15) * KP + kb;
                bh[nt] = *(const bf16x8*)&xs_hi[ro];
                bl[nt] = *(const bf16x8*)&xs_lo[ro];
            }
            #pragma unroll
            for (int ct = 0; ct < 4; ++ct) {
                int wo = (ct * 16 + l15) * 128 + kb;
                ah[ct] = *(const bf16x8*)(wh + wo);
                al[ct] = *(const bf16x8*)(wl + wo);
            }
            #pragma unroll
            for (int ct = 0; ct < 4; ++ct)
                #pragma unroll
                for (int nt = 0; nt < 2; ++nt) {
                    acc[nt][ct] = __builtin_amdgcn_mfma_f32_16x16x32_bf16(
                        ah[ct], bh[nt], acc[nt][ct], 0, 0, 0);
                    acc[nt][ct] = __builtin_amdgcn_mfma_f32_16x16x32_bf16(
                        ah[ct], bl[nt], acc[nt][ct], 0, 0, 0);
                    acc[nt][ct] = __builtin_amdgcn_mfma_f32_16x16x32_bf16(
                        al[ct], bh[nt], acc[nt][ct], 0, 0, 0);
                }
        }
        const int* ipr = ip + (size_t)r * N;
        size_t rb = (size_t)r * N;
        #pragma unroll
        for (int nt = 0; nt < 2; ++nt) {
            int xrow = row0 + nbase + nt * 16 + l15;
            if (xrow < N) {
                int nrow = ipr[xrow];
                #pragma unroll
                for (int ct = 0; ct < 4; ++ct) {
                    f32x4 a = acc[nt][ct];
                    ushort4 v;
                    v.x = f2bf(a.x); v.y = f2bf(a.y);
                    v.z = f2bf(a.z); v.w = f2bf(a.w);
                    int cb = ct * 16 + lhi * 4;
                    *(ushort4*)(combined + (rb + xrow) * 128 + cb) = v;
                    *(ushort4*)(combined + (rb + nrow) * 128 + 64 + cb) = v;
                }
            }
        }
    }
}

// ---------------- gather: one wave per (r, dst row); fused epilogue ---------
__global__ __launch_bounds__(256) void gather_kernel(const int2* __restrict__ csr,
                                                     const int* __restrict__ rowstart,
                                                     const float* __restrict__ dinv,
                                                     const unsigned short* __restrict__ combined,
                                                     const float* __restrict__ bs,
                                                     float* __restrict__ out_pos,
                                                     float* __restrict__ out_neg,
                                                     float* __restrict__ partial,
                                                     int N, int E) {
    int r = blockIdx.y;
    int lane = threadIdx.x & 63, wv = threadIdx.x >> 6;
    int i = blockIdx.x * 4 + wv;
    i = __builtin_amdgcn_readfirstlane(i);      // wave-uniform, make it scalar
    int c0 = (lane & 31) * 2;                   // output channel pair base
    __shared__ float ls[4][64];
    float p0 = 0.f, p1 = 0.f;                   // pos values for summary
    if (i < N) {
        const unsigned short* cw = combined + (size_t)r * N * 128;
        const int* rs = rowstart + (size_t)r * (N + 1);
        int j0 = rs[i], j1 = rs[i + 1];
        j0 = __builtin_amdgcn_readfirstlane(j0);
        j1 = __builtin_amdgcn_readfirstlane(j1);
        float di = dinv[(size_t)r * N + i];
        float w = di * di;
        // self term: whole 256B row in one coalesced wave access
        unsigned int sv = *(const unsigned int*)(cw + (size_t)i * 128 + 2 * lane);
        float acc0 = bf2f((unsigned short)sv) * w;
        float acc1 = bf2f((unsigned short)(sv >> 16)) * w;
        const int2* cs = csr + (size_t)r * E;
        int last = j1 - 1;
        for (int j = j0; j < j1; j += 8) {
            int2 e[8];
            float nm[8];
            #pragma unroll
            for (int k = 0; k < 8; ++k) {
                int idx = j + k;
                int ic = idx < last ? idx : last;        // clamp: always valid
                e[k] = cs[ic];                            // scalar load (uniform)
                nm[k] = (idx < j1) ? __int_as_float(e[k].y) : 0.f;
            }
            #pragma unroll
            for (int k = 0; k < 8; ++k) {
                unsigned int v = *(const unsigned int*)(cw + (size_t)e[k].x * 128 + 2 * lane);
                acc0 += bf2f((unsigned short)v) * nm[k];
                acc1 += bf2f((unsigned short)(v >> 16)) * nm[k];
            }
        }
        float2 bv = *(const float2*)(bs + r * F_OUT + c0);
        float q0 = acc0 + bv.x; q0 = q0 > 0.f ? q0 : 0.f;
        float q1 = acc1 + bv.y; q1 = q1 > 0.f ? q1 : 0.f;
        size_t off = (size_t)r * N * F_OUT + (size_t)i * F_OUT + c0;
        float* dst = (lane < 32) ? (out_pos + off) : (out_neg + off);
        f32x2 o; o.x = q0; o.y = q1;
        __builtin_nontemporal_store(o, (f32x2*)dst);
        if (lane < 32) { p0 = q0; p1 = q1; }
    }
    if (lane < 32) { ls[wv][c0] = p0; ls[wv][c0 + 1] = p1; }
    __syncthreads();
    if (wv == 0) {
        float t = ls[0][lane] + ls[1][lane] + ls[2][lane] + ls[3][lane];
        atomicAdd(&partial[((size_t)r * 256 + (blockIdx.x & 255)) * F_OUT + lane], t);
    }
}

// ---------------- summary = mean over pos rows ------------------------------
__global__ __launch_bounds__(256) void summary_reduce(const float* __restrict__ partial,
                                                      float* __restrict__ summary,
                                                      float inv_n) {
    int r = blockIdx.x;
    int lane = threadIdx.x & 63, wv = threadIdx.x >> 6;
    __shared__ float ls[256];
    float s = 0.f;
    for (int c = wv; c < 256; c += 4)
        s += partial[((size_t)r * 256 + c) * F_OUT + lane];
    ls[threadIdx.x] = s;
    __syncthreads();
    if (wv == 0)
        summary[r * F_OUT + lane] =
            (ls[lane] + ls[64 + lane] + ls[128 + lane] + ls[192 + lane]) * inv_n;
}

extern "C" void kernel_launch(void* const* d_in, const int* in_sizes, int n_in,
                              void* d_out, int out_size, void* d_ws, size_t ws_size,
                              hipStream_t stream) {
    const float* x    = (const float*)d_in[0];
    const int*   ei   = (const int*)d_in[1];
    const int*   perm = (const int*)d_in[2];
    const float* Ws   = (const float*)d_in[3];
    const float* bs   = (const float*)d_in[4];

    const int N = in_sizes[0] / F_IN;          // 100000
    const int R = in_sizes[4] / F_OUT;         // 3
    const int E = in_sizes[1] / (2 * R);       // 600000

    float* out_pos = (float*)d_out;
    float* out_neg = out_pos + (size_t)R * N * F_OUT;
    float* summary = out_neg + (size_t)R * N * F_OUT;

    char* ws = (char*)d_ws;
    size_t off = 0;
    auto alloc = [&](size_t bytes) { void* p = ws + off;
        off += (bytes + 255) & ~(size_t)255; return p; };
    int*   deg      = (int*)  alloc((size_t)R * N * 4);   // -> cursor after scan
    float* dinv     = (float*)alloc((size_t)R * N * 4);
    int*   rowstart = (int*)  alloc((size_t)R * (N + 1) * 4);
    int*   ip       = (int*)  alloc((size_t)R * N * 4);
    int2*  csr      = (int2*) alloc((size_t)R * E * 8);
    unsigned short* combined = (unsigned short*)alloc((size_t)R * N * 128 * 2);
    float* partial  = (float*)alloc((size_t)R * 256 * F_OUT * 4);
    int*   psum     = (int*)  alloc((size_t)R * NCHUNK * 4);
    unsigned short* wt_hi = (unsigned short*)alloc((size_t)R * 64 * 128 * 2);
    unsigned short* wt_lo = (unsigned short*)alloc((size_t)R * 64 * 128 * 2);

    const int chunk = (N + NCHUNK - 1) / NCHUNK;

    hipMemsetAsync(deg, 0, (size_t)R * N * sizeof(int), stream);
    hipMemsetAsync(partial, 0, (size_t)R * 256 * F_OUT * sizeof(float), stream);

    deg_kernel<<<dim3((E + 255) / 256, R), 256, 0, stream>>>(ei, deg, N, E);
    invperm_kernel<<<dim3((N + 255) / 256, R), 256, 0, stream>>>(perm, ip, N);
    w_convert<<<(R * 64 * 128 + 255) / 256, 256, 0, stream>>>(Ws, wt_hi, wt_lo, R);
    scan_partial<<<dim3(NCHUNK, R), 256, 0, stream>>>(deg, psum, N, chunk);
    scan_offsets<<<1, 256, 0, stream>>>(psum, rowstart, N, R);
    scan_apply<<<dim3(NCHUNK, R), 256, 0, stream>>>(deg, psum, rowstart, dinv, N, chunk);
    fill_csr<<<dim3((E + 255) / 256, R), 256, 0, stream>>>(ei, dinv, deg, csr, N, E);
    gemm_xw_mfma<<<(N + 127) / 128, 256, 0, stream>>>(x, wt_hi, wt_lo, ip, combined, N, R);
    gather_kernel<<<dim3((N + 3) / 4, R), 256, 0, stream>>>(csr, rowstart, dinv,
                                                            combined, bs, out_pos,
                                                            out_neg, partial, N, E);
    summary_reduce<<<R, 256, 0, stream>>>(partial, summary, 1.0f / (float)N);
}

// Round 5
// 544.248 us; speedup vs baseline: 1.0078x; 1.0078x over previous
//
#include <hip/hip_runtime.h>

#define F_IN 128
#define F_OUT 64
#define NCHUNK 256   // scan chunks per relation

typedef float f32x2 __attribute__((ext_vector_type(2)));
typedef float f32x4 __attribute__((ext_vector_type(4)));
typedef short bf16x8 __attribute__((ext_vector_type(8)));

__device__ __forceinline__ unsigned short f2bf(float f) {
    unsigned int u = __float_as_uint(f);
    u += 0x7fff + ((u >> 16) & 1);          // round-nearest-even
    return (unsigned short)(u >> 16);
}
__device__ __forceinline__ float bf2f(unsigned short s) {
    return __uint_as_float((unsigned int)s << 16);
}

// ---------------- prep: deg atomics | invperm | w_convert (block-partition) -
__global__ __launch_bounds__(256) void prep_kernel(const int* __restrict__ ei,
                                                   const int* __restrict__ perm,
                                                   const float* __restrict__ W,
                                                   int* __restrict__ deg,
                                                   int* __restrict__ ip,
                                                   unsigned short* __restrict__ wt_hi,
                                                   unsigned short* __restrict__ wt_lo,
                                                   int N, int E, int R,
                                                   int degB, int invB) {
    int b = blockIdx.x;
    if (b < degB) {                       // degree histogram
        int idx = b * 256 + threadIdx.x;
        if (idx < R * E) {
            int r = idx / E, e = idx - r * E;
            int d = ei[(size_t)r * 2 * E + E + e];
            atomicAdd(&deg[(size_t)r * N + d], 1);
        }
    } else if (b < degB + invB) {         // inverse permutation
        int idx = (b - degB) * 256 + threadIdx.x;
        if (idx < R * N) {
            int r = idx / N, i = idx - r * N;
            ip[(size_t)r * N + perm[idx]] = i;
        }
    } else {                              // W -> bf16 hi/lo transpose
        int idx = (b - degB - invB) * 256 + threadIdx.x;
        if (idx < R * 64 * 128) {
            int k = idx & 127, c = (idx >> 7) & 63, r = idx >> 13;
            float v = W[((size_t)r * F_IN + k) * F_OUT + c];
            unsigned short h = f2bf(v);
            wt_hi[idx] = h;
            wt_lo[idx] = f2bf(v - bf2f(h));
        }
    }
}

// ---------------- scan phase 1: per-chunk sums (grid = R*NCHUNK) ------------
__global__ __launch_bounds__(256) void scan_partial(const int* __restrict__ deg,
                                                    int* __restrict__ psum,
                                                    int N, int chunk) {
    int b = blockIdx.x;
    int r = b >> 8, c = b & 255;
    int start = c * chunk, end = min(start + chunk, N);
    int s = 0;
    for (int i = start + threadIdx.x; i < end; i += 256)
        s += deg[(size_t)r * N + i];
    __shared__ int ls[256];
    ls[threadIdx.x] = s;
    __syncthreads();
    for (int off = 128; off > 0; off >>= 1) {
        if (threadIdx.x < off) ls[threadIdx.x] += ls[threadIdx.x + off];
        __syncthreads();
    }
    if (threadIdx.x == 0) psum[b] = ls[0];
}

// ---------------- scan phase 2: each block re-derives offsets, applies ------
// Replaces scan_offsets (1-block dispatch) + scan_apply. Every block scans its
// relation's 256 chunk sums (cheap, redundant) to get its own base.
__global__ __launch_bounds__(256) void scan_apply2(int* __restrict__ deg,
                                                   const int* __restrict__ psum,
                                                   int* __restrict__ rowstart,
                                                   float* __restrict__ dinv,
                                                   int N, int chunk) {
    int b = blockIdx.x;
    int r = b >> 8, c = b & 255;
    int tid = threadIdx.x, lane = tid & 63, wv = tid >> 6;
    __shared__ int incl[256];
    __shared__ int wsum[4];

    // block-wide inclusive scan of this relation's chunk sums
    int pv = psum[(r << 8) + tid];
    int sc = pv;
    #pragma unroll
    for (int off = 1; off < 64; off <<= 1) {
        int t = __shfl_up(sc, off, 64);
        if (lane >= off) sc += t;
    }
    if (lane == 63) wsum[wv] = sc;
    __syncthreads();
    int woff = 0;
    for (int w = 0; w < wv; ++w) woff += wsum[w];
    incl[tid] = woff + sc;
    __syncthreads();
    int base = (c == 0) ? 0 : incl[c - 1];
    if (c == 0 && tid == 0)
        rowstart[(size_t)r * (N + 1) + N] = incl[255];    // relation total

    // apply within chunk (4 elems/thread)
    int start = c * chunk, end = min(start + chunk, N);
    int* dg = deg + (size_t)r * N;
    int* rs = rowstart + (size_t)r * (N + 1);
    float* dv = dinv + (size_t)r * N;
    int v[4]; int tsum = 0;
    #pragma unroll
    for (int j = 0; j < 4; ++j) {
        int idx = start + tid * 4 + j;
        v[j] = (idx < end) ? dg[idx] : 0;
        tsum += v[j];
    }
    int sc2 = tsum;
    #pragma unroll
    for (int off = 1; off < 64; off <<= 1) {
        int t = __shfl_up(sc2, off, 64);
        if (lane >= off) sc2 += t;
    }
    if (lane == 63) wsum[wv] = sc2;     // safe: all old wsum reads done pre-sync
    __syncthreads();
    int woff2 = 0;
    for (int w = 0; w < wv; ++w) woff2 += wsum[w];
    int excl = base + woff2 + sc2 - tsum;
    #pragma unroll
    for (int j = 0; j < 4; ++j) {
        int idx = start + tid * 4 + j;
        if (idx < end) {
            rs[idx] = excl;
            dg[idx] = excl;                       // cursor for fill phase
            dv[idx] = rsqrtf((float)(v[j] + 1));  // +1 self-loop
        }
        excl += v[j];
    }
}

// ---------------- fused: MFMA gemm (blocks [0,gemmB)) + fill_csr (rest) -----
// Independent chains overlap in one dispatch. Gemm re-tiled to 64 rows so the
// kernel's static LDS (34.8 KB) keeps 4 blocks/CU for both roles.
// mfma_f32_16x16x32_bf16, operands swapped (A=W^T, B=x^T): D col=lane&15=x row,
// row=(lane>>4)*4+reg = out channel -> ushort4 packed stores.
__global__ __launch_bounds__(256) void fill_gemm(const int* __restrict__ ei,
                                                 const float* __restrict__ dinv,
                                                 int* __restrict__ cursor,
                                                 int2* __restrict__ csr,
                                                 const float* __restrict__ x,
                                                 const unsigned short* __restrict__ wt_hi,
                                                 const unsigned short* __restrict__ wt_lo,
                                                 const int* __restrict__ ip,
                                                 unsigned short* __restrict__ combined,
                                                 int N, int E, int R, int gemmB) {
    constexpr int KP = 136;   // row stride: 272B, 16B-aligned, 2-way bank alias (free)
    __shared__ __align__(16) unsigned short xs_hi[64 * KP];
    __shared__ __align__(16) unsigned short xs_lo[64 * KP];
    int b = blockIdx.x;

    if (b >= gemmB) {   // ---- fill_csr role ----
        int idx = (b - gemmB) * 256 + threadIdx.x;
        if (idx >= R * E) return;
        int r = idx / E, e = idx - r * E;
        const int* base = ei + (size_t)r * 2 * E;
        int s = base[e], d = base[E + e];
        const float* dv = dinv + (size_t)r * N;
        float nrm = dv[s] * dv[d];
        int pos = atomicAdd(&cursor[(size_t)r * N + d], 1);
        int2 sp; sp.x = s; sp.y = __float_as_int(nrm);
        csr[(size_t)r * E + pos] = sp;
        return;
    }

    // ---- gemm role: 64-row tile ----
    int row0 = b * 64;
    int tid = threadIdx.x;
    {   // stage x tile as bf16 hi/lo: thread -> (row = tid>>2, 32-col quarter)
        int rr = tid >> 2, q = tid & 3;
        int grow = row0 + rr; if (grow >= N) grow = N - 1;   // clamp, never stored
        const float* xr = x + (size_t)grow * F_IN + q * 32;
        unsigned short* dh = &xs_hi[rr * KP + q * 32];
        unsigned short* dl = &xs_lo[rr * KP + q * 32];
        #pragma unroll
        for (int c = 0; c < 32; c += 4) {
            float4 v = *(const float4*)(xr + c);
            unsigned short h0 = f2bf(v.x), h1 = f2bf(v.y),
                           h2 = f2bf(v.z), h3 = f2bf(v.w);
            ushort4 hv; hv.x = h0; hv.y = h1; hv.z = h2; hv.w = h3;
            *(ushort4*)(dh + c) = hv;
            ushort4 lv;
            lv.x = f2bf(v.x - bf2f(h0)); lv.y = f2bf(v.y - bf2f(h1));
            lv.z = f2bf(v.z - bf2f(h2)); lv.w = f2bf(v.w - bf2f(h3));
            *(ushort4*)(dl + c) = lv;
        }
    }
    __syncthreads();

    int wv = tid >> 6, lane = tid & 63;
    int l15 = lane & 15, lhi = lane >> 4;
    int nbase = wv * 16;                        // wave owns 16 x-rows
    for (int r = 0; r < R; ++r) {
        f32x4 acc[4];
        #pragma unroll
        for (int ct = 0; ct < 4; ++ct) acc[ct] = (f32x4){0.f, 0.f, 0.f, 0.f};
        const unsigned short* wh = wt_hi + (size_t)r * 64 * 128;
        const unsigned short* wl = wt_lo + (size_t)r * 64 * 128;
        #pragma unroll
        for (int kc = 0; kc < 4; ++kc) {
            int kb = kc * 32 + lhi * 8;
            int ro = (nbase + l15) * KP + kb;
            bf16x8 bh = *(const bf16x8*)&xs_hi[ro];
            bf16x8 bl = *(const bf16x8*)&xs_lo[ro];
            bf16x8 ah[4], al[4];
            #pragma unroll
            for (int ct = 0; ct < 4; ++ct) {
                int wo = (ct * 16 + l15) * 128 + kb;
                ah[ct] = *(const bf16x8*)(wh + wo);
                al[ct] = *(const bf16x8*)(wl + wo);
            }
            #pragma unroll
            for (int ct = 0; ct < 4; ++ct) {
                acc[ct] = __builtin_amdgcn_mfma_f32_16x16x32_bf16(ah[ct], bh, acc[ct], 0, 0, 0);
                acc[ct] = __builtin_amdgcn_mfma_f32_16x16x32_bf16(ah[ct], bl, acc[ct], 0, 0, 0);
                acc[ct] = __builtin_amdgcn_mfma_f32_16x16x32_bf16(al[ct], bh, acc[ct], 0, 0, 0);
            }
        }
        const int* ipr = ip + (size_t)r * N;
        size_t rb = (size_t)r * N;
        int xrow = row0 + nbase + l15;
        if (xrow < N) {
            int nrow = ipr[xrow];
            #pragma unroll
            for (int ct = 0; ct < 4; ++ct) {
                f32x4 a = acc[ct];
                ushort4 v;
                v.x = f2bf(a.x); v.y = f2bf(a.y);
                v.z = f2bf(a.z); v.w = f2bf(a.w);
                int cb = ct * 16 + lhi * 4;
                *(ushort4*)(combined + (rb + xrow) * 128 + cb) = v;
                *(ushort4*)(combined + (rb + nrow) * 128 + 64 + cb) = v;
            }
        }
    }
}

// ---------------- gather: one wave per (r, dst row); fused epilogue ---------
__global__ __launch_bounds__(256) void gather_kernel(const int2* __restrict__ csr,
                                                     const int* __restrict__ rowstart,
                                                     const float* __restrict__ dinv,
                                                     const unsigned short* __restrict__ combined,
                                                     const float* __restrict__ bs,
                                                     float* __restrict__ out_pos,
                                                     float* __restrict__ out_neg,
                                                     float* __restrict__ partial,
                                                     int N, int E) {
    int r = blockIdx.y;
    int lane = threadIdx.x & 63, wv = threadIdx.x >> 6;
    int i = blockIdx.x * 4 + wv;
    i = __builtin_amdgcn_readfirstlane(i);      // wave-uniform, make it scalar
    int c0 = (lane & 31) * 2;                   // output channel pair base
    __shared__ float ls[4][64];
    float p0 = 0.f, p1 = 0.f;                   // pos values for summary
    if (i < N) {
        const unsigned short* cw = combined + (size_t)r * N * 128;
        const int* rs = rowstart + (size_t)r * (N + 1);
        int j0 = rs[i], j1 = rs[i + 1];
        j0 = __builtin_amdgcn_readfirstlane(j0);
        j1 = __builtin_amdgcn_readfirstlane(j1);
        float di = dinv[(size_t)r * N + i];
        float w = di * di;
        // self term: whole 256B row in one coalesced wave access
        unsigned int sv = *(const unsigned int*)(cw + (size_t)i * 128 + 2 * lane);
        float acc0 = bf2f((unsigned short)sv) * w;
        float acc1 = bf2f((unsigned short)(sv >> 16)) * w;
        const int2* cs = csr + (size_t)r * E;
        int last = j1 - 1;
        for (int j = j0; j < j1; j += 8) {
            int2 e[8];
            float nm[8];
            #pragma unroll
            for (int k = 0; k < 8; ++k) {
                int idx = j + k;
                int ic = idx < last ? idx : last;        // clamp: always valid
                e[k] = cs[ic];                            // scalar load (uniform)
                nm[k] = (idx < j1) ? __int_as_float(e[k].y) : 0.f;
            }
            #pragma unroll
            for (int k = 0; k < 8; ++k) {
                unsigned int v = *(const unsigned int*)(cw + (size_t)e[k].x * 128 + 2 * lane);
                acc0 += bf2f((unsigned short)v) * nm[k];
                acc1 += bf2f((unsigned short)(v >> 16)) * nm[k];
            }
        }
        float2 bv = *(const float2*)(bs + r * F_OUT + c0);
        float q0 = acc0 + bv.x; q0 = q0 > 0.f ? q0 : 0.f;
        float q1 = acc1 + bv.y; q1 = q1 > 0.f ? q1 : 0.f;
        size_t off = (size_t)r * N * F_OUT + (size_t)i * F_OUT + c0;
        float* dst = (lane < 32) ? (out_pos + off) : (out_neg + off);
        f32x2 o; o.x = q0; o.y = q1;
        __builtin_nontemporal_store(o, (f32x2*)dst);
        if (lane < 32) { p0 = q0; p1 = q1; }
    }
    if (lane < 32) { ls[wv][c0] = p0; ls[wv][c0 + 1] = p1; }
    __syncthreads();
    if (wv == 0) {
        float t = ls[0][lane] + ls[1][lane] + ls[2][lane] + ls[3][lane];
        atomicAdd(&partial[((size_t)r * 256 + (blockIdx.x & 255)) * F_OUT + lane], t);
    }
}

// ---------------- summary = mean over pos rows ------------------------------
__global__ __launch_bounds__(256) void summary_reduce(const float* __restrict__ partial,
                                                      float* __restrict__ summary,
                                                      float inv_n) {
    int r = blockIdx.x;
    int lane = threadIdx.x & 63, wv = threadIdx.x >> 6;
    __shared__ float ls[256];
    float s = 0.f;
    for (int c = wv; c < 256; c += 4)
        s += partial[((size_t)r * 256 + c) * F_OUT + lane];
    ls[threadIdx.x] = s;
    __syncthreads();
    if (wv == 0)
        summary[r * F_OUT + lane] =
            (ls[lane] + ls[64 + lane] + ls[128 + lane] + ls[192 + lane]) * inv_n;
}

extern "C" void kernel_launch(void* const* d_in, const int* in_sizes, int n_in,
                              void* d_out, int out_size, void* d_ws, size_t ws_size,
                              hipStream_t stream) {
    const float* x    = (const float*)d_in[0];
    const int*   ei   = (const int*)d_in[1];
    const int*   perm = (const int*)d_in[2];
    const float* Ws   = (const float*)d_in[3];
    const float* bs   = (const float*)d_in[4];

    const int N = in_sizes[0] / F_IN;          // 100000
    const int R = in_sizes[4] / F_OUT;         // 3
    const int E = in_sizes[1] / (2 * R);       // 600000

    float* out_pos = (float*)d_out;
    float* out_neg = out_pos + (size_t)R * N * F_OUT;
    float* summary = out_neg + (size_t)R * N * F_OUT;

    char* ws = (char*)d_ws;
    size_t off = 0;
    auto alloc = [&](size_t bytes) { void* p = ws + off;
        off += (bytes + 255) & ~(size_t)255; return p; };
    // deg + partial contiguous -> single memset
    int*   deg      = (int*)  alloc((size_t)R * N * 4);   // -> cursor after scan
    float* partial  = (float*)alloc((size_t)R * 256 * F_OUT * 4);
    float* dinv     = (float*)alloc((size_t)R * N * 4);
    int*   rowstart = (int*)  alloc((size_t)R * (N + 1) * 4);
    int*   ip       = (int*)  alloc((size_t)R * N * 4);
    int2*  csr      = (int2*) alloc((size_t)R * E * 8);
    unsigned short* combined = (unsigned short*)alloc((size_t)R * N * 128 * 2);
    int*   psum     = (int*)  alloc((size_t)R * NCHUNK * 4);
    unsigned short* wt_hi = (unsigned short*)alloc((size_t)R * 64 * 128 * 2);
    unsigned short* wt_lo = (unsigned short*)alloc((size_t)R * 64 * 128 * 2);

    const int chunk = (N + NCHUNK - 1) / NCHUNK;
    const int degB = (R * E + 255) / 256;
    const int invB = (R * N + 255) / 256;
    const int wB   = (R * 64 * 128 + 255) / 256;
    const int gemmB = (N + 63) / 64;

    size_t zbytes = (size_t)((char*)dinv - (char*)deg);   // deg + partial
    hipMemsetAsync(deg, 0, zbytes, stream);

    prep_kernel<<<degB + invB + wB, 256, 0, stream>>>(ei, perm, Ws, deg, ip,
                                                      wt_hi, wt_lo, N, E, R,
                                                      degB, invB);
    scan_partial<<<R * NCHUNK, 256, 0, stream>>>(deg, psum, N, chunk);
    scan_apply2<<<R * NCHUNK, 256, 0, stream>>>(deg, psum, rowstart, dinv, N, chunk);
    fill_gemm<<<gemmB + degB, 256, 0, stream>>>(ei, dinv, deg, csr, x, wt_hi,
                                                wt_lo, ip, combined, N, E, R, gemmB);
    gather_kernel<<<dim3((N + 3) / 4, R), 256, 0, stream>>>(csr, rowstart, dinv,
                                                            combined, bs, out_pos,
                                                            out_neg, partial, N, E);
    summary_reduce<<<R, 256, 0, stream>>>(partial, summary, 1.0f / (float)N);
}

// Round 6
// 529.643 us; speedup vs baseline: 1.0356x; 1.0276x over previous
//
#include <hip/hip_runtime.h>

#define F_IN 128
#define F_OUT 64
#define NCHUNK 256   // scan chunks per relation

typedef float f32x2 __attribute__((ext_vector_type(2)));
typedef float f32x4 __attribute__((ext_vector_type(4)));
typedef short bf16x8 __attribute__((ext_vector_type(8)));

__device__ __forceinline__ unsigned short f2bf(float f) {
    unsigned int u = __float_as_uint(f);
    u += 0x7fff + ((u >> 16) & 1);          // round-nearest-even
    return (unsigned short)(u >> 16);
}
__device__ __forceinline__ float bf2f(unsigned short s) {
    return __uint_as_float((unsigned int)s << 16);
}

// ---- prep: deg atomics (+slot record) | invperm | w_convert (block-split) --
__global__ __launch_bounds__(256) void prep_kernel(const int* __restrict__ ei,
                                                   const int* __restrict__ perm,
                                                   const float* __restrict__ W,
                                                   int* __restrict__ deg,
                                                   int* __restrict__ eoff,
                                                   int* __restrict__ ip,
                                                   unsigned short* __restrict__ wt_hi,
                                                   unsigned short* __restrict__ wt_lo,
                                                   int N, int E, int R,
                                                   int degB, int invB) {
    int b = blockIdx.x;
    if (b < degB) {                       // degree histogram + per-edge slot
        int idx = b * 256 + threadIdx.x;
        if (idx < R * E) {
            int r = idx / E, e = idx - r * E;
            int d = ei[(size_t)r * 2 * E + E + e];
            int pos = atomicAdd(&deg[(size_t)r * N + d], 1);
            eoff[idx] = pos;              // slot within dst row (atomic order)
        }
    } else if (b < degB + invB) {         // inverse permutation
        int idx = (b - degB) * 256 + threadIdx.x;
        if (idx < R * N) {
            int r = idx / N, i = idx - r * N;
            ip[(size_t)r * N + perm[idx]] = i;
        }
    } else {                              // W -> bf16 hi/lo transpose
        int idx = (b - degB - invB) * 256 + threadIdx.x;
        if (idx < R * 64 * 128) {
            int k = idx & 127, c = (idx >> 7) & 63, r = idx >> 13;
            float v = W[((size_t)r * F_IN + k) * F_OUT + c];
            unsigned short h = f2bf(v);
            wt_hi[idx] = h;
            wt_lo[idx] = f2bf(v - bf2f(h));
        }
    }
}

// ---------------- scan phase 1: per-chunk sums (grid = R*NCHUNK) ------------
__global__ __launch_bounds__(256) void scan_partial(const int* __restrict__ deg,
                                                    int* __restrict__ psum,
                                                    int N, int chunk) {
    int b = blockIdx.x;
    int r = b >> 8, c = b & 255;
    int start = c * chunk, end = min(start + chunk, N);
    int s = 0;
    for (int i = start + threadIdx.x; i < end; i += 256)
        s += deg[(size_t)r * N + i];
    __shared__ int ls[256];
    ls[threadIdx.x] = s;
    __syncthreads();
    for (int off = 128; off > 0; off >>= 1) {
        if (threadIdx.x < off) ls[threadIdx.x] += ls[threadIdx.x + off];
        __syncthreads();
    }
    if (threadIdx.x == 0) psum[b] = ls[0];
}

// ---------------- scan phase 2: each block re-derives offsets, applies ------
__global__ __launch_bounds__(256) void scan_apply2(const int* __restrict__ deg,
                                                   const int* __restrict__ psum,
                                                   int* __restrict__ rowstart,
                                                   float* __restrict__ dinv,
                                                   int N, int chunk) {
    int b = blockIdx.x;
    int r = b >> 8, c = b & 255;
    int tid = threadIdx.x, lane = tid & 63, wv = tid >> 6;
    __shared__ int incl[256];
    __shared__ int wsum[4];

    // block-wide inclusive scan of this relation's chunk sums
    int pv = psum[(r << 8) + tid];
    int sc = pv;
    #pragma unroll
    for (int off = 1; off < 64; off <<= 1) {
        int t = __shfl_up(sc, off, 64);
        if (lane >= off) sc += t;
    }
    if (lane == 63) wsum[wv] = sc;
    __syncthreads();
    int woff = 0;
    for (int w = 0; w < wv; ++w) woff += wsum[w];
    incl[tid] = woff + sc;
    __syncthreads();
    int base = (c == 0) ? 0 : incl[c - 1];
    if (c == 0 && tid == 0)
        rowstart[(size_t)r * (N + 1) + N] = incl[255];    // relation total

    // apply within chunk (4 elems/thread)
    int start = c * chunk, end = min(start + chunk, N);
    const int* dg = deg + (size_t)r * N;
    int* rs = rowstart + (size_t)r * (N + 1);
    float* dv = dinv + (size_t)r * N;
    int v[4]; int tsum = 0;
    #pragma unroll
    for (int j = 0; j < 4; ++j) {
        int idx = start + tid * 4 + j;
        v[j] = (idx < end) ? dg[idx] : 0;
        tsum += v[j];
    }
    int sc2 = tsum;
    #pragma unroll
    for (int off = 1; off < 64; off <<= 1) {
        int t = __shfl_up(sc2, off, 64);
        if (lane >= off) sc2 += t;
    }
    if (lane == 63) wsum[wv] = sc2;     // safe: all old wsum reads done pre-sync
    __syncthreads();
    int woff2 = 0;
    for (int w = 0; w < wv; ++w) woff2 += wsum[w];
    int excl = base + woff2 + sc2 - tsum;
    #pragma unroll
    for (int j = 0; j < 4; ++j) {
        int idx = start + tid * 4 + j;
        if (idx < end) {
            rs[idx] = excl;
            dv[idx] = rsqrtf((float)(v[j] + 1));  // +1 self-loop
        }
        excl += v[j];
    }
}

// ---------------- MFMA gemm (64-row tile): combined = bf16(x @ W_r) ---------
// mfma_f32_16x16x32_bf16, operands swapped (A=W^T, B=x^T): D col=lane&15=x row,
// row=(lane>>4)*4+reg = out channel -> ushort4 packed stores.
__global__ __launch_bounds__(256) void gemm_xw(const float* __restrict__ x,
                                               const unsigned short* __restrict__ wt_hi,
                                               const unsigned short* __restrict__ wt_lo,
                                               const int* __restrict__ ip,
                                               unsigned short* __restrict__ combined,
                                               int N, int R) {
    constexpr int KP = 136;   // row stride: 272B, 16B-aligned, 2-way bank alias (free)
    __shared__ __align__(16) unsigned short xs_hi[64 * KP];
    __shared__ __align__(16) unsigned short xs_lo[64 * KP];

    int row0 = blockIdx.x * 64;
    int tid = threadIdx.x;
    {   // stage x tile as bf16 hi/lo: thread -> (row = tid>>2, 32-col quarter)
        int rr = tid >> 2, q = tid & 3;
        int grow = row0 + rr; if (grow >= N) grow = N - 1;   // clamp, never stored
        const float* xr = x + (size_t)grow * F_IN + q * 32;
        unsigned short* dh = &xs_hi[rr * KP + q * 32];
        unsigned short* dl = &xs_lo[rr * KP + q * 32];
        #pragma unroll
        for (int c = 0; c < 32; c += 4) {
            float4 v = *(const float4*)(xr + c);
            unsigned short h0 = f2bf(v.x), h1 = f2bf(v.y),
                           h2 = f2bf(v.z), h3 = f2bf(v.w);
            ushort4 hv; hv.x = h0; hv.y = h1; hv.z = h2; hv.w = h3;
            *(ushort4*)(dh + c) = hv;
            ushort4 lv;
            lv.x = f2bf(v.x - bf2f(h0)); lv.y = f2bf(v.y - bf2f(h1));
            lv.z = f2bf(v.z - bf2f(h2)); lv.w = f2bf(v.w - bf2f(h3));
            *(ushort4*)(dl + c) = lv;
        }
    }
    __syncthreads();

    int wv = tid >> 6, lane = tid & 63;
    int l15 = lane & 15, lhi = lane >> 4;
    int nbase = wv * 16;                        // wave owns 16 x-rows
    for (int r = 0; r < R; ++r) {
        f32x4 acc[4];
        #pragma unroll
        for (int ct = 0; ct < 4; ++ct) acc[ct] = (f32x4){0.f, 0.f, 0.f, 0.f};
        const unsigned short* wh = wt_hi + (size_t)r * 64 * 128;
        const unsigned short* wl = wt_lo + (size_t)r * 64 * 128;
        #pragma unroll
        for (int kc = 0; kc < 4; ++kc) {
            int kb = kc * 32 + lhi * 8;
            int ro = (nbase + l15) * KP + kb;
            bf16x8 bh = *(const bf16x8*)&xs_hi[ro];
            bf16x8 bl = *(const bf16x8*)&xs_lo[ro];
            bf16x8 ah[4], al[4];
            #pragma unroll
            for (int ct = 0; ct < 4; ++ct) {
                int wo = (ct * 16 + l15) * 128 + kb;
                ah[ct] = *(const bf16x8*)(wh + wo);
                al[ct] = *(const bf16x8*)(wl + wo);
            }
            #pragma unroll
            for (int ct = 0; ct < 4; ++ct) {
                acc[ct] = __builtin_amdgcn_mfma_f32_16x16x32_bf16(ah[ct], bh, acc[ct], 0, 0, 0);
                acc[ct] = __builtin_amdgcn_mfma_f32_16x16x32_bf16(ah[ct], bl, acc[ct], 0, 0, 0);
                acc[ct] = __builtin_amdgcn_mfma_f32_16x16x32_bf16(al[ct], bh, acc[ct], 0, 0, 0);
            }
        }
        const int* ipr = ip + (size_t)r * N;
        size_t rb = (size_t)r * N;
        int xrow = row0 + nbase + l15;
        if (xrow < N) {
            int nrow = ipr[xrow];
            #pragma unroll
            for (int ct = 0; ct < 4; ++ct) {
                f32x4 a = acc[ct];
                ushort4 v;
                v.x = f2bf(a.x); v.y = f2bf(a.y);
                v.z = f2bf(a.z); v.w = f2bf(a.w);
                int cb = ct * 16 + lhi * 4;
                *(ushort4*)(combined + (rb + xrow) * 128 + cb) = v;
                *(ushort4*)(combined + (rb + nrow) * 128 + 64 + cb) = v;
            }
        }
    }
}

// ---------------- fill CSR, no atomics: slot precomputed in prep ------------
__global__ __launch_bounds__(256) void fill_csr2(const int* __restrict__ ei,
                                                 const int* __restrict__ eoff,
                                                 const int* __restrict__ rowstart,
                                                 const float* __restrict__ dinv,
                                                 int2* __restrict__ csr,
                                                 int N, int E, int R) {
    int idx = blockIdx.x * 256 + threadIdx.x;
    if (idx >= R * E) return;
    int r = idx / E, e = idx - r * E;
    const int* base = ei + (size_t)r * 2 * E;
    int s = base[e], d = base[E + e];
    const float* dv = dinv + (size_t)r * N;
    float nrm = dv[s] * dv[d];
    int pos = rowstart[(size_t)r * (N + 1) + d] + eoff[idx];
    int2 sp; sp.x = s; sp.y = __float_as_int(nrm);
    csr[(size_t)r * E + pos] = sp;
}

// ---------------- gather: one wave per dst row; relation-major block order --
// 1-D grid, r = bid / perRel: relation-r blocks run (mostly) together, so the
// per-relation combined (25.6 MB) stays L3-resident instead of 3x77 MB
// thrashing against the output stream.
__global__ __launch_bounds__(256) void gather_kernel(const int2* __restrict__ csr,
                                                     const int* __restrict__ rowstart,
                                                     const float* __restrict__ dinv,
                                                     const unsigned short* __restrict__ combined,
                                                     const float* __restrict__ bs,
                                                     float* __restrict__ out_pos,
                                                     float* __restrict__ out_neg,
                                                     float* __restrict__ partial,
                                                     int N, int E, int perRel) {
    int bid = blockIdx.x;
    int r = bid / perRel, ib = bid - r * perRel;
    int lane = threadIdx.x & 63, wv = threadIdx.x >> 6;
    int i = ib * 4 + wv;
    i = __builtin_amdgcn_readfirstlane(i);      // wave-uniform, make it scalar
    int c0 = (lane & 31) * 2;                   // output channel pair base
    __shared__ float ls[4][64];
    float p0 = 0.f, p1 = 0.f;                   // pos values for summary
    if (i < N) {
        const unsigned short* cw = combined + (size_t)r * N * 128;
        const int* rs = rowstart + (size_t)r * (N + 1);
        int j0 = rs[i], j1 = rs[i + 1];
        j0 = __builtin_amdgcn_readfirstlane(j0);
        j1 = __builtin_amdgcn_readfirstlane(j1);
        float di = dinv[(size_t)r * N + i];
        float w = di * di;
        // self term: whole 256B row in one coalesced wave access
        unsigned int sv = *(const unsigned int*)(cw + (size_t)i * 128 + 2 * lane);
        float acc0 = bf2f((unsigned short)sv) * w;
        float acc1 = bf2f((unsigned short)(sv >> 16)) * w;
        const int2* cs = csr + (size_t)r * E;
        int last = j1 - 1;
        for (int j = j0; j < j1; j += 8) {
            int2 e[8];
            float nm[8];
            #pragma unroll
            for (int k = 0; k < 8; ++k) {
                int idx = j + k;
                int ic = idx < last ? idx : last;        // clamp: always valid
                e[k] = cs[ic];                            // scalar load (uniform)
                nm[k] = (idx < j1) ? __int_as_float(e[k].y) : 0.f;
            }
            #pragma unroll
            for (int k = 0; k < 8; ++k) {
                unsigned int v = *(const unsigned int*)(cw + (size_t)e[k].x * 128 + 2 * lane);
                acc0 += bf2f((unsigned short)v) * nm[k];
                acc1 += bf2f((unsigned short)(v >> 16)) * nm[k];
            }
        }
        float2 bv = *(const float2*)(bs + r * F_OUT + c0);
        float q0 = acc0 + bv.x; q0 = q0 > 0.f ? q0 : 0.f;
        float q1 = acc1 + bv.y; q1 = q1 > 0.f ? q1 : 0.f;
        size_t off = (size_t)r * N * F_OUT + (size_t)i * F_OUT + c0;
        float* dst = (lane < 32) ? (out_pos + off) : (out_neg + off);
        f32x2 o; o.x = q0; o.y = q1;
        __builtin_nontemporal_store(o, (f32x2*)dst);
        if (lane < 32) { p0 = q0; p1 = q1; }
    }
    if (lane < 32) { ls[wv][c0] = p0; ls[wv][c0 + 1] = p1; }
    __syncthreads();
    if (wv == 0) {
        float t = ls[0][lane] + ls[1][lane] + ls[2][lane] + ls[3][lane];
        atomicAdd(&partial[((size_t)r * 256 + (ib & 255)) * F_OUT + lane], t);
    }
}

// ---------------- summary = mean over pos rows ------------------------------
__global__ __launch_bounds__(256) void summary_reduce(const float* __restrict__ partial,
                                                      float* __restrict__ summary,
                                                      float inv_n) {
    int r = blockIdx.x;
    int lane = threadIdx.x & 63, wv = threadIdx.x >> 6;
    __shared__ float ls[256];
    float s = 0.f;
    for (int c = wv; c < 256; c += 4)
        s += partial[((size_t)r * 256 + c) * F_OUT + lane];
    ls[threadIdx.x] = s;
    __syncthreads();
    if (wv == 0)
        summary[r * F_OUT + lane] =
            (ls[lane] + ls[64 + lane] + ls[128 + lane] + ls[192 + lane]) * inv_n;
}

extern "C" void kernel_launch(void* const* d_in, const int* in_sizes, int n_in,
                              void* d_out, int out_size, void* d_ws, size_t ws_size,
                              hipStream_t stream) {
    const float* x    = (const float*)d_in[0];
    const int*   ei   = (const int*)d_in[1];
    const int*   perm = (const int*)d_in[2];
    const float* Ws   = (const float*)d_in[3];
    const float* bs   = (const float*)d_in[4];

    const int N = in_sizes[0] / F_IN;          // 100000
    const int R = in_sizes[4] / F_OUT;         // 3
    const int E = in_sizes[1] / (2 * R);       // 600000

    float* out_pos = (float*)d_out;
    float* out_neg = out_pos + (size_t)R * N * F_OUT;
    float* summary = out_neg + (size_t)R * N * F_OUT;

    char* ws = (char*)d_ws;
    size_t off = 0;
    auto alloc = [&](size_t bytes) { void* p = ws + off;
        off += (bytes + 255) & ~(size_t)255; return p; };
    // deg + partial contiguous -> single memset
    int*   deg      = (int*)  alloc((size_t)R * N * 4);
    float* partial  = (float*)alloc((size_t)R * 256 * F_OUT * 4);
    float* dinv     = (float*)alloc((size_t)R * N * 4);
    int*   rowstart = (int*)  alloc((size_t)R * (N + 1) * 4);
    int*   ip       = (int*)  alloc((size_t)R * N * 4);
    int*   eoff     = (int*)  alloc((size_t)R * E * 4);
    int2*  csr      = (int2*) alloc((size_t)R * E * 8);
    unsigned short* combined = (unsigned short*)alloc((size_t)R * N * 128 * 2);
    int*   psum     = (int*)  alloc((size_t)R * NCHUNK * 4);
    unsigned short* wt_hi = (unsigned short*)alloc((size_t)R * 64 * 128 * 2);
    unsigned short* wt_lo = (unsigned short*)alloc((size_t)R * 64 * 128 * 2);

    const int chunk = (N + NCHUNK - 1) / NCHUNK;
    const int degB = (R * E + 255) / 256;
    const int invB = (R * N + 255) / 256;
    const int wB   = (R * 64 * 128 + 255) / 256;
    const int gemmB = (N + 63) / 64;
    const int perRel = (N + 3) / 4;

    size_t zbytes = (size_t)((char*)dinv - (char*)deg);   // deg + partial
    hipMemsetAsync(deg, 0, zbytes, stream);

    prep_kernel<<<degB + invB + wB, 256, 0, stream>>>(ei, perm, Ws, deg, eoff,
                                                      ip, wt_hi, wt_lo, N, E, R,
                                                      degB, invB);
    scan_partial<<<R * NCHUNK, 256, 0, stream>>>(deg, psum, N, chunk);
    scan_apply2<<<R * NCHUNK, 256, 0, stream>>>(deg, psum, rowstart, dinv, N, chunk);
    gemm_xw<<<gemmB, 256, 0, stream>>>(x, wt_hi, wt_lo, ip, combined, N, R);
    fill_csr2<<<(R * E + 255) / 256, 256, 0, stream>>>(ei, eoff, rowstart, dinv,
                                                       csr, N, E, R);
    gather_kernel<<<perRel * R, 256, 0, stream>>>(csr, rowstart, dinv, combined,
                                                  bs, out_pos, out_neg, partial,
                                                  N, E, perRel);
    summary_reduce<<<R, 256, 0, stream>>>(partial, summary, 1.0f / (float)N);
}